// Round 10
// baseline (759.530 us; speedup 1.0000x reference)
//
#include <hip/hip_runtime.h>

#define TT 2000
#define BB 64
#define HH 256
#define BH (BB*HH)
#define CH 8            // chunk = 8 time steps
#define NCH (TT/CH)     // 250 chunks
#define CROWS 128       // w_recP rows cached in LDS (s in [0,128) = masks m0,m1)

__device__ __forceinline__ float clip01(float x) { return fminf(fmaxf(x, 0.0f), 1.0f); }

// ---------------- weight prep ----------------
// w_inT[k][h]        = w_in[h][k]    (GEMM)
// w_recP[s][4l+j]    = w_rec[l+64j][s]  (packed gather rows; R7-verified transform)
__global__ void transpose2(const float* __restrict__ w_in, const float* __restrict__ w_rec,
                           float* __restrict__ w_inT, float* __restrict__ w_recP) {
    int idx = blockIdx.x * 256 + threadIdx.x;   // 65536 per matrix
    int h = idx >> 8, s = idx & 255;            // coalesced read over s
    w_inT[s * HH + h] = w_in[idx];
    int l = h & 63, j = h >> 6;
    w_recP[s * HH + 4 * l + j] = w_rec[idx];
}

// ---------------- f32 GEMM: xw[n,h] = sum_k X[n,k] * w_inT[k,h] ----------------
#define BM 128
#define BN 128
#define BK 32
__global__ __launch_bounds__(256) void gemm_xw(const float* __restrict__ X,
                                               const float* __restrict__ WT,
                                               float* __restrict__ OutXW) {
    __shared__ __align__(16) float XsT[BK][BM + 4];   // transposed: [k][row]
    __shared__ __align__(16) float Ws[BK][BN + 4];    // [k][col]
    int tid = threadIdx.x;
    int n0 = blockIdx.x * BM;
    int h0 = blockIdx.y * BN;
    int ty = tid >> 4, tx = tid & 15;
    float acc[8][8] = {};

    for (int kc = 0; kc < HH; kc += BK) {
        {
            int r = tid & 127, kseg = (tid >> 7) * 16;
            const float* src = X + (size_t)(n0 + r) * HH + kc + kseg;
#pragma unroll
            for (int q = 0; q < 4; q++) {
                float4 xv = *(const float4*)(src + q * 4);
                XsT[kseg + q * 4 + 0][r] = xv.x;
                XsT[kseg + q * 4 + 1][r] = xv.y;
                XsT[kseg + q * 4 + 2][r] = xv.z;
                XsT[kseg + q * 4 + 3][r] = xv.w;
            }
        }
        {
            int krow = tid >> 3, cs = (tid & 7) * 16;
            const float* src = WT + (size_t)(kc + krow) * HH + h0 + cs;
#pragma unroll
            for (int q = 0; q < 4; q++) {
                float4 wv = *(const float4*)(src + q * 4);
                *(float4*)&Ws[krow][cs + q * 4] = wv;
            }
        }
        __syncthreads();
#pragma unroll 4
        for (int kk = 0; kk < BK; kk++) {
            float4 a0 = *(const float4*)&XsT[kk][ty * 8];
            float4 a1 = *(const float4*)&XsT[kk][ty * 8 + 4];
            float4 b0 = *(const float4*)&Ws[kk][tx * 8];
            float4 b1 = *(const float4*)&Ws[kk][tx * 8 + 4];
            float a[8] = {a0.x, a0.y, a0.z, a0.w, a1.x, a1.y, a1.z, a1.w};
            float bb[8] = {b0.x, b0.y, b0.z, b0.w, b1.x, b1.y, b1.z, b1.w};
#pragma unroll
            for (int r = 0; r < 8; r++)
#pragma unroll
                for (int c = 0; c < 8; c++)
                    acc[r][c] += a[r] * bb[c];
        }
        __syncthreads();
    }
#pragma unroll
    for (int r = 0; r < 8; r++) {
        int n = n0 + ty * 8 + r;
        int b = n / TT;
        int t = n - b * TT;
        float* dst = OutXW + ((size_t)t * BB + b) * HH + h0 + tx * 8;
        float4 s0 = {acc[r][0], acc[r][1], acc[r][2], acc[r][3]};
        float4 s1 = {acc[r][4], acc[r][5], acc[r][6], acc[r][7]};
        *(float4*)dst = s0;
        *(float4*)(dst + 4) = s1;
    }
}

// ---------------- sequential LIF scan ----------------
// Consumer (wave0): dynamics + one-step-deferred spike gather. Its vmcnt queue
// holds ONLY the 4 high-half slot loads (spike stores done by producer).
// Producer (wave1): stages packed xw chunk c+1 -> LDS ring; reconstructs chunk
// c-1's spikes from LDS masks and NT-stores them.
// Sum order per neuron: m0 asc, m1 asc (LDS wcache), m2 asc, m3 asc (global)
// == R9's passing order; fma with wt in {0,1} and dummy rows is fp-exact.

// extract next index (ascending) from mask pair A(=bits 0..63), B(=64..127)
#define EX1(A, B, SOUT) do {                                                        \
    bool _ua = ((A) != 0ull);                                                       \
    unsigned long long _pk = _ua ? (A) : (B);                                       \
    int _bit = (int)__builtin_ctzll(_pk | 0x8000000000000000ull);                   \
    SOUT = (_ua ? 0 : 64) + _bit;                                                   \
    unsigned long long _pc = _pk & (_pk - 1ull);                                    \
    A = _ua ? _pc : (A);                                                            \
    B = _ua ? (B) : _pc;                                                            \
} while (0)

__global__ __launch_bounds__(128) void scan_lif(const float* __restrict__ tau_syn,
                                                const float* __restrict__ tau_mem,
                                                const float* __restrict__ w_recP,
                                                float* __restrict__ outp) {
    const float DT = 0.001f;
    __shared__ __align__(16) float ring[2 * CH * HH];          // 16 KB, packed rows
    __shared__ __align__(16) float wc[CROWS * HH];             // 128 KB: w_recP rows 0..127
    __shared__ __align__(16) unsigned long long mb[2][CH][4];  // 512 B: spike masks
    int b = blockIdx.x;
    int lane = threadIdx.x & 63;
    int wid = threadIdx.x >> 6;

    // ---- cooperative wcache fill: straight copy of w_recP rows 0..127 ----
    {
        const float4* src = (const float4*)w_recP;
        float4* dst = (float4*)wc;
#pragma unroll
        for (int q = 0; q < (CROWS * HH / 4) / 128; ++q)   // 64 iters
            dst[q * 128 + threadIdx.x] = src[q * 128 + threadIdx.x];
    }

    if (wid == 1) {
        // ---- producer ----
        // pre-stage chunk 0 (packed: component j = xw[h=lane+64j])
        {
            float a0[CH], a1[CH], a2[CH], a3[CH];
#pragma unroll
            for (int r = 0; r < CH; ++r) {
                const float* base = outp + ((size_t)r * BB + b) * HH;
                a0[r] = base[lane]; a1[r] = base[lane + 64];
                a2[r] = base[lane + 128]; a3[r] = base[lane + 192];
            }
#pragma unroll
            for (int r = 0; r < CH; ++r) {
                float4 v = {a0[r], a1[r], a2[r], a3[r]};
                *(float4*)&ring[r * HH + 4 * lane] = v;
            }
        }
        __syncthreads();
        for (int c = 0; c < NCH; ++c) {
            if (c + 1 < NCH) {
                int t0 = (c + 1) * CH;
                int lb2 = ((c + 1) & 1) * (CH * HH);
                float a0[CH], a1[CH], a2[CH], a3[CH];
#pragma unroll
                for (int r = 0; r < CH; ++r) {
                    const float* base = outp + ((size_t)(t0 + r) * BB + b) * HH;
                    a0[r] = base[lane]; a1[r] = base[lane + 64];
                    a2[r] = base[lane + 128]; a3[r] = base[lane + 192];
                }
#pragma unroll
                for (int r = 0; r < CH; ++r) {
                    float4 v = {a0[r], a1[r], a2[r], a3[r]};
                    *(float4*)&ring[lb2 + r * HH + 4 * lane] = v;
                }
            }
            if (c > 0) {
                int cc = c - 1, ms = cc & 1, t0 = cc * CH;
#pragma unroll
                for (int u = 0; u < CH; ++u) {
                    unsigned long long q0 = mb[ms][u][0], q1 = mb[ms][u][1];
                    unsigned long long q2 = mb[ms][u][2], q3 = mb[ms][u][3];
                    float* dst = outp + ((size_t)(t0 + u) * BB + b) * HH + lane;
                    __builtin_nontemporal_store(((q0 >> lane) & 1) ? 1.0f : 0.0f, dst);
                    __builtin_nontemporal_store(((q1 >> lane) & 1) ? 1.0f : 0.0f, dst + 64);
                    __builtin_nontemporal_store(((q2 >> lane) & 1) ? 1.0f : 0.0f, dst + 128);
                    __builtin_nontemporal_store(((q3 >> lane) & 1) ? 1.0f : 0.0f, dst + 192);
                }
            }
            __syncthreads();
        }
        {   // last chunk's spikes
            int cc = NCH - 1, ms = cc & 1, t0 = cc * CH;
#pragma unroll
            for (int u = 0; u < CH; ++u) {
                unsigned long long q0 = mb[ms][u][0], q1 = mb[ms][u][1];
                unsigned long long q2 = mb[ms][u][2], q3 = mb[ms][u][3];
                float* dst = outp + ((size_t)(t0 + u) * BB + b) * HH + lane;
                __builtin_nontemporal_store(((q0 >> lane) & 1) ? 1.0f : 0.0f, dst);
                __builtin_nontemporal_store(((q1 >> lane) & 1) ? 1.0f : 0.0f, dst + 64);
                __builtin_nontemporal_store(((q2 >> lane) & 1) ? 1.0f : 0.0f, dst + 128);
                __builtin_nontemporal_store(((q3 >> lane) & 1) ? 1.0f : 0.0f, dst + 192);
            }
        }
        return;
    }

    // ---- consumer wave ----
    float am[4], bs[4];
#pragma unroll
    for (int j = 0; j < 4; j++) {
        am[j] = DT * clip01(tau_mem[lane + 64 * j]);
        bs[j] = DT * clip01(tau_syn[lane + 64 * j]);
    }

    float vv[4] = {0.f, 0.f, 0.f, 0.f};
    float ii[4] = {0.f, 0.f, 0.f, 0.f};
    float zl[4] = {0.f, 0.f, 0.f, 0.f};
    // deferred-gather state (single-buffered; read at step t+1 before overwrite)
    float4 slL0 = {0,0,0,0}, slL1 = {0,0,0,0}, slL2 = {0,0,0,0}, slL3 = {0,0,0,0};
    float4 slH0 = {0,0,0,0}, slH1 = {0,0,0,0}, slH2 = {0,0,0,0}, slH3 = {0,0,0,0};
    float wtL0 = 0.f, wtL1 = 0.f, wtL2 = 0.f, wtL3 = 0.f;
    float wtH0 = 0.f, wtH1 = 0.f, wtH2 = 0.f, wtH3 = 0.f;
    unsigned long long pm0 = 0, pm1 = 0, pm2 = 0, pm3 = 0;
    bool fbp = false;

    __syncthreads();   // wcache + chunk 0 staged

    for (int c = 0; c < NCH; ++c) {
        int lb = (c & 1) * (CH * HH);
#pragma unroll
        for (int u = 0; u < CH; ++u) {
            // xw row (packed): component j = xw[h=lane+64j]
            float4 cur = *(const float4*)&ring[lb + u * HH + 4 * lane];
            // dynamics
            bool zz[4]; float id[4];
#pragma unroll
            for (int j = 0; j < 4; j++) {
                float vd = vv[j] + am[j] * (ii[j] - vv[j]);   // v + DT*tmi*(-v+i)
                id[j] = ii[j] - bs[j] * ii[j];                // i - DT*tsi*i
                zz[j] = (vd - 1.0f) > 0.0f;
                float zf = zz[j] ? 1.0f : 0.0f;
                vv[j] = zz[j] ? 0.0f : vd;
                zl[j] = zf;
            }
            unsigned long long m0 = __ballot(zz[0]);
            unsigned long long m1 = __ballot(zz[1]);
            unsigned long long m2 = __ballot(zz[2]);
            unsigned long long m3 = __ballot(zz[3]);
            if (lane == 0) {
                ulonglong2 w01; w01.x = m0; w01.y = m1;
                ulonglong2 w23; w23.x = m2; w23.y = m3;
                *(ulonglong2*)&mb[c & 1][u][0] = w01;
                *(ulonglong2*)&mb[c & 1][u][2] = w23;
            }
            // accumulate PREVIOUS step's spikes (slots are one step old)
            float r0, r1, r2, r3;
            if (fbp) {
                r0 = 0.f; r1 = 0.f; r2 = 0.f; r3 = 0.f;
                unsigned long long m;
                m = pm0; while (m) { int bit = __builtin_ctzll(m); m &= m - 1;
                    float4 e = *(const float4*)(wc + (bit << 8) + 4 * lane);
                    r0 += e.x; r1 += e.y; r2 += e.z; r3 += e.w; }
                m = pm1; while (m) { int bit = __builtin_ctzll(m); m &= m - 1;
                    float4 e = *(const float4*)(wc + ((64 + bit) << 8) + 4 * lane);
                    r0 += e.x; r1 += e.y; r2 += e.z; r3 += e.w; }
                m = pm2; while (m) { int bit = __builtin_ctzll(m); m &= m - 1;
                    float4 e = *(const float4*)(w_recP + ((size_t)(128 + bit) << 8) + 4 * lane);
                    r0 += e.x; r1 += e.y; r2 += e.z; r3 += e.w; }
                m = pm3; while (m) { int bit = __builtin_ctzll(m); m &= m - 1;
                    float4 e = *(const float4*)(w_recP + ((size_t)(192 + bit) << 8) + 4 * lane);
                    r0 += e.x; r1 += e.y; r2 += e.z; r3 += e.w; }
            } else {
                r0 = 0.f; r1 = 0.f; r2 = 0.f; r3 = 0.f;
                r0 += wtL0 * slL0.x; r1 += wtL0 * slL0.y; r2 += wtL0 * slL0.z; r3 += wtL0 * slL0.w;
                r0 += wtL1 * slL1.x; r1 += wtL1 * slL1.y; r2 += wtL1 * slL1.z; r3 += wtL1 * slL1.w;
                r0 += wtL2 * slL2.x; r1 += wtL2 * slL2.y; r2 += wtL2 * slL2.z; r3 += wtL2 * slL2.w;
                r0 += wtL3 * slL3.x; r1 += wtL3 * slL3.y; r2 += wtL3 * slL3.z; r3 += wtL3 * slL3.w;
                r0 += wtH0 * slH0.x; r1 += wtH0 * slH0.y; r2 += wtH0 * slH0.z; r3 += wtH0 * slH0.w;
                r0 += wtH1 * slH1.x; r1 += wtH1 * slH1.y; r2 += wtH1 * slH1.z; r3 += wtH1 * slH1.w;
                r0 += wtH2 * slH2.x; r1 += wtH2 * slH2.y; r2 += wtH2 * slH2.z; r3 += wtH2 * slH2.w;
                r0 += wtH3 * slH3.x; r1 += wtH3 * slH3.y; r2 += wtH3 * slH3.z; r3 += wtH3 * slH3.w;
            }
            ii[0] = (id[0] + cur.x) + r0;
            ii[1] = (id[1] + cur.y) + r1;
            ii[2] = (id[2] + cur.z) + r2;
            ii[3] = (id[3] + cur.w) + r3;
            // extract + issue THIS step's spikes (consumed next step)
            int cntL = __popcll(m0) + __popcll(m1);
            int cntH = __popcll(m2) + __popcll(m3);
            pm0 = m0; pm1 = m1; pm2 = m2; pm3 = m3;
            fbp = (cntL > 4) || (cntH > 4);
            wtL0 = (cntL > 0) ? 1.0f : 0.0f; wtL1 = (cntL > 1) ? 1.0f : 0.0f;
            wtL2 = (cntL > 2) ? 1.0f : 0.0f; wtL3 = (cntL > 3) ? 1.0f : 0.0f;
            wtH0 = (cntH > 0) ? 1.0f : 0.0f; wtH1 = (cntH > 1) ? 1.0f : 0.0f;
            wtH2 = (cntH > 2) ? 1.0f : 0.0f; wtH3 = (cntH > 3) ? 1.0f : 0.0f;
            if (cntL) {
                unsigned long long a = m0, bq = m1;
                int s0, s1, s2, s3;
                EX1(a, bq, s0); EX1(a, bq, s1); EX1(a, bq, s2); EX1(a, bq, s3);
                slL0 = *(const float4*)(wc + (s0 << 8) + 4 * lane);
                slL1 = *(const float4*)(wc + (s1 << 8) + 4 * lane);
                slL2 = *(const float4*)(wc + (s2 << 8) + 4 * lane);
                slL3 = *(const float4*)(wc + (s3 << 8) + 4 * lane);
            }
            if (cntH) {
                unsigned long long a = m2, bq = m3;
                int s0, s1, s2, s3;
                EX1(a, bq, s0); EX1(a, bq, s1); EX1(a, bq, s2); EX1(a, bq, s3);
                slH0 = *(const float4*)(w_recP + ((size_t)(128 + s0) << 8) + 4 * lane);
                slH1 = *(const float4*)(w_recP + ((size_t)(128 + s1) << 8) + 4 * lane);
                slH2 = *(const float4*)(w_recP + ((size_t)(128 + s2) << 8) + 4 * lane);
                slH3 = *(const float4*)(w_recP + ((size_t)(128 + s3) << 8) + 4 * lane);
            }
        }
        __syncthreads();
    }

    // final state: z_f, v_f, i_f (from registers)
#pragma unroll
    for (int j = 0; j < 4; j++) {
        outp[(size_t)TT * BH + b * HH + lane + 64 * j] = zl[j];
        outp[(size_t)TT * BH + BH + b * HH + lane + 64 * j] = vv[j];
        outp[(size_t)TT * BH + 2 * BH + b * HH + lane + 64 * j] = ii[j];
    }
}

extern "C" void kernel_launch(void* const* d_in, const int* in_sizes, int n_in,
                              void* d_out, int out_size, void* d_ws, size_t ws_size,
                              hipStream_t stream) {
    const float* x       = (const float*)d_in[0];
    const float* w_in    = (const float*)d_in[1];
    const float* w_rec   = (const float*)d_in[2];
    const float* tau_syn = (const float*)d_in[3];
    const float* tau_mem = (const float*)d_in[4];
    float* out = (float*)d_out;

    float* w_inT  = (float*)d_ws;           // 65536 floats
    float* w_recP = w_inT + HH * HH;        // 65536 floats

    transpose2<<<256, 256, 0, stream>>>(w_in, w_rec, w_inT, w_recP);

    dim3 ggrid((BB * TT) / BM, HH / BN);    // (1000, 2)
    gemm_xw<<<ggrid, 256, 0, stream>>>(x, w_inT, out);

    scan_lif<<<BB, 128, 0, stream>>>(tau_syn, tau_mem, w_recP, out);
}

// Round 11
// 619.637 us; speedup vs baseline: 1.2258x; 1.2258x over previous
//
#include <hip/hip_runtime.h>

#define TT 2000
#define BB 64
#define HH 256
#define BH (BB*HH)
#define CH 8            // chunk = 8 time steps
#define NCH (TT/CH)     // 250 chunks
#define CROWS 128       // w_recP rows cached in LDS (s in [0,128))

__device__ __forceinline__ float clip01(float x) { return fminf(fmaxf(x, 0.0f), 1.0f); }

// ---------------- weight prep ----------------
// w_inT[k][h]     = w_in[h][k]       (GEMM)
// w_recP[s][4l+j] = w_rec[l+64j][s]  (packed gather rows; R10-verified)
__global__ void transpose2(const float* __restrict__ w_in, const float* __restrict__ w_rec,
                           float* __restrict__ w_inT, float* __restrict__ w_recP) {
    int idx = blockIdx.x * 256 + threadIdx.x;   // 65536 per matrix
    int h = idx >> 8, s = idx & 255;            // coalesced read over s
    w_inT[s * HH + h] = w_in[idx];
    int l = h & 63, j = h >> 6;
    w_recP[s * HH + 4 * l + j] = w_rec[idx];
}

// ---------------- f32 GEMM: xw[n,h] = sum_k X[n,k] * w_inT[k,h] ----------------
// K accumulated ascending k=0..255 per output (kc asc, kk asc) — bitwise-stable.
#define BM 128
#define BN 128
#define BK 64
__global__ __launch_bounds__(256) void gemm_xw(const float* __restrict__ X,
                                               const float* __restrict__ WT,
                                               float* __restrict__ OutXW) {
    __shared__ __align__(16) float XsT[BK][BM + 4];   // transposed: [k][row] 33.8KB
    __shared__ __align__(16) float Ws[BK][BN + 4];    // [k][col]            33.8KB
    int tid = threadIdx.x;
    int n0 = blockIdx.x * BM;
    int h0 = blockIdx.y * BN;
    int ty = tid >> 4, tx = tid & 15;
    float acc[8][8] = {};

    for (int kc = 0; kc < HH; kc += BK) {
        {   // X tile 128 rows x 64 k, transposed into LDS
            int r = tid & 127, kseg = (tid >> 7) * 32;
            const float* src = X + (size_t)(n0 + r) * HH + kc + kseg;
#pragma unroll
            for (int q = 0; q < 8; q++) {
                float4 xv = *(const float4*)(src + q * 4);
                XsT[kseg + q * 4 + 0][r] = xv.x;
                XsT[kseg + q * 4 + 1][r] = xv.y;
                XsT[kseg + q * 4 + 2][r] = xv.z;
                XsT[kseg + q * 4 + 3][r] = xv.w;
            }
        }
        {   // W tile 64 k x 128 cols (contiguous)
            int krow = tid >> 2, cs = (tid & 3) * 32;
            const float* src = WT + (size_t)(kc + krow) * HH + h0 + cs;
#pragma unroll
            for (int q = 0; q < 8; q++) {
                float4 wv = *(const float4*)(src + q * 4);
                *(float4*)&Ws[krow][cs + q * 4] = wv;
            }
        }
        __syncthreads();
#pragma unroll 4
        for (int kk = 0; kk < BK; kk++) {
            float4 a0 = *(const float4*)&XsT[kk][ty * 8];
            float4 a1 = *(const float4*)&XsT[kk][ty * 8 + 4];
            float4 b0 = *(const float4*)&Ws[kk][tx * 8];
            float4 b1 = *(const float4*)&Ws[kk][tx * 8 + 4];
            float a[8] = {a0.x, a0.y, a0.z, a0.w, a1.x, a1.y, a1.z, a1.w};
            float bb[8] = {b0.x, b0.y, b0.z, b0.w, b1.x, b1.y, b1.z, b1.w};
#pragma unroll
            for (int r = 0; r < 8; r++)
#pragma unroll
                for (int c = 0; c < 8; c++)
                    acc[r][c] += a[r] * bb[c];
        }
        __syncthreads();
    }
#pragma unroll
    for (int r = 0; r < 8; r++) {
        int n = n0 + ty * 8 + r;
        int b = n / TT;
        int t = n - b * TT;
        float* dst = OutXW + ((size_t)t * BB + b) * HH + h0 + tx * 8;
        float4 s0 = {acc[r][0], acc[r][1], acc[r][2], acc[r][3]};
        float4 s1 = {acc[r][4], acc[r][5], acc[r][6], acc[r][7]};
        *(float4*)dst = s0;
        *(float4*)(dst + 4) = s1;
    }
}

// ---------------- sequential LIF scan ----------------
// R9 skeleton (immediate in-step gather, racc carried as 4 floats only).
// NEW: within a step, spike loads are BATCHED — extract all indices (SALU),
// issue global loads then LDS loads back-to-back, wait once, accumulate in
// ascending m0,m1 (LDS wc) then m2,m3 (global) order. Dummy slots use weight
// 0.0 (fma(0,x,r)=r exact; fma(1,x,r)=x+r exact). >4 spikes in a half ->
// serial fallback in identical order (R10-verified values/order).

// extract next index (ascending) from mask pair A(bits 0..63) B(64..127)
#define EX1(A, B, SOUT) do {                                                        \
    bool _ua = ((A) != 0ull);                                                       \
    unsigned long long _pk = _ua ? (A) : (B);                                       \
    int _bit = (int)__builtin_ctzll(_pk | 0x8000000000000000ull);                   \
    SOUT = (_ua ? 0 : 64) + _bit;                                                   \
    unsigned long long _pc = _pk & (_pk - 1ull);                                    \
    A = _ua ? _pc : (A);                                                            \
    B = _ua ? (B) : _pc;                                                            \
} while (0)

#define STEP()                                                                      \
    do {                                                                            \
        bool z[4]; float id[4];                                                     \
        _Pragma("unroll")                                                           \
        for (int j = 0; j < 4; j++) {                                               \
            float vd = vv[j] + am[j] * (ii[j] - vv[j]);     /* v + DT*tmi*(-v+i) */ \
            id[j] = ii[j] - bs[j] * ii[j];                  /* i - DT*tsi*i    */   \
            z[j] = (vd - 1.0f) > 0.0f;                                              \
            float zf = z[j] ? 1.0f : 0.0f;                                          \
            vv[j] = z[j] ? 0.0f : vd;                                               \
            ii[j] = (id[j] + cur[j]) + racc[j];             /* (i_dec+xw)+rec */    \
            __builtin_nontemporal_store(zf, &outp[stoff + j * 64]);                 \
            zl[j] = zf;                                                             \
        }                                                                           \
        stoff += BH;                                                                \
        unsigned long long m0 = __ballot(z[0]);                                     \
        unsigned long long m1 = __ballot(z[1]);                                     \
        unsigned long long m2 = __ballot(z[2]);                                     \
        unsigned long long m3 = __ballot(z[3]);                                     \
        racc[0] = 0.0f; racc[1] = 0.0f; racc[2] = 0.0f; racc[3] = 0.0f;             \
        if ((m0 | m1 | m2 | m3) != 0ull) {                                          \
            int cntL = __popcll(m0) + __popcll(m1);                                 \
            int cntH = __popcll(m2) + __popcll(m3);                                 \
            if (cntL <= 4 && cntH <= 4) {                                           \
                unsigned long long a, bq;                                           \
                int sH0, sH1, sH2, sH3, sL0, sL1, sL2, sL3;                         \
                a = m2; bq = m3;                                                    \
                EX1(a, bq, sH0); EX1(a, bq, sH1); EX1(a, bq, sH2); EX1(a, bq, sH3); \
                /* issue global (L2) loads first — longest latency */               \
                float4 eH0 = *(const float4*)(w_recP + ((size_t)(128 + sH0) << 8) + 4 * lane); \
                float4 eH1 = *(const float4*)(w_recP + ((size_t)(128 + sH1) << 8) + 4 * lane); \
                float4 eH2 = *(const float4*)(w_recP + ((size_t)(128 + sH2) << 8) + 4 * lane); \
                float4 eH3 = *(const float4*)(w_recP + ((size_t)(128 + sH3) << 8) + 4 * lane); \
                a = m0; bq = m1;                                                    \
                EX1(a, bq, sL0); EX1(a, bq, sL1); EX1(a, bq, sL2); EX1(a, bq, sL3); \
                float4 eL0 = *(const float4*)(wc + (sL0 << 8) + 4 * lane);          \
                float4 eL1 = *(const float4*)(wc + (sL1 << 8) + 4 * lane);          \
                float4 eL2 = *(const float4*)(wc + (sL2 << 8) + 4 * lane);          \
                float4 eL3 = *(const float4*)(wc + (sL3 << 8) + 4 * lane);          \
                float wL0 = (cntL > 0) ? 1.0f : 0.0f, wL1 = (cntL > 1) ? 1.0f : 0.0f; \
                float wL2 = (cntL > 2) ? 1.0f : 0.0f, wL3 = (cntL > 3) ? 1.0f : 0.0f; \
                float wH0 = (cntH > 0) ? 1.0f : 0.0f, wH1 = (cntH > 1) ? 1.0f : 0.0f; \
                float wH2 = (cntH > 2) ? 1.0f : 0.0f, wH3 = (cntH > 3) ? 1.0f : 0.0f; \
                float r0 = 0.f, r1 = 0.f, r2 = 0.f, r3 = 0.f;                       \
                r0 += wL0 * eL0.x; r1 += wL0 * eL0.y; r2 += wL0 * eL0.z; r3 += wL0 * eL0.w; \
                r0 += wL1 * eL1.x; r1 += wL1 * eL1.y; r2 += wL1 * eL1.z; r3 += wL1 * eL1.w; \
                r0 += wL2 * eL2.x; r1 += wL2 * eL2.y; r2 += wL2 * eL2.z; r3 += wL2 * eL2.w; \
                r0 += wL3 * eL3.x; r1 += wL3 * eL3.y; r2 += wL3 * eL3.z; r3 += wL3 * eL3.w; \
                r0 += wH0 * eH0.x; r1 += wH0 * eH0.y; r2 += wH0 * eH0.z; r3 += wH0 * eH0.w; \
                r0 += wH1 * eH1.x; r1 += wH1 * eH1.y; r2 += wH1 * eH1.z; r3 += wH1 * eH1.w; \
                r0 += wH2 * eH2.x; r1 += wH2 * eH2.y; r2 += wH2 * eH2.z; r3 += wH2 * eH2.w; \
                r0 += wH3 * eH3.x; r1 += wH3 * eH3.y; r2 += wH3 * eH3.z; r3 += wH3 * eH3.w; \
                racc[0] = r0; racc[1] = r1; racc[2] = r2; racc[3] = r3;             \
            } else {                                                                \
                unsigned long long m;                                               \
                m = m0; while (m) { int bit = __builtin_ctzll(m); m &= m - 1;       \
                    float4 e = *(const float4*)(wc + (bit << 8) + 4 * lane);        \
                    racc[0] += e.x; racc[1] += e.y; racc[2] += e.z; racc[3] += e.w; } \
                m = m1; while (m) { int bit = __builtin_ctzll(m); m &= m - 1;       \
                    float4 e = *(const float4*)(wc + ((64 + bit) << 8) + 4 * lane); \
                    racc[0] += e.x; racc[1] += e.y; racc[2] += e.z; racc[3] += e.w; } \
                m = m2; while (m) { int bit = __builtin_ctzll(m); m &= m - 1;       \
                    float4 e = *(const float4*)(w_recP + ((size_t)(128 + bit) << 8) + 4 * lane); \
                    racc[0] += e.x; racc[1] += e.y; racc[2] += e.z; racc[3] += e.w; } \
                m = m3; while (m) { int bit = __builtin_ctzll(m); m &= m - 1;       \
                    float4 e = *(const float4*)(w_recP + ((size_t)(192 + bit) << 8) + 4 * lane); \
                    racc[0] += e.x; racc[1] += e.y; racc[2] += e.z; racc[3] += e.w; } \
            }                                                                       \
        }                                                                           \
    } while (0)

__global__ __launch_bounds__(128) void scan_lif(const float* __restrict__ tau_syn,
                                                const float* __restrict__ tau_mem,
                                                const float* __restrict__ w_recP,
                                                float* __restrict__ outp) {
    const float DT = 0.001f;
    __shared__ __align__(16) float ring[2 * CH * HH];     // 16 KB (unpacked rows)
    __shared__ __align__(16) float wc[CROWS * HH];        // 128 KB: w_recP rows 0..127
    int b = blockIdx.x;
    int lane = threadIdx.x & 63;
    int wid = threadIdx.x >> 6;

    // ---- cooperative wcache fill: straight copy of w_recP rows 0..127 ----
    {
        const float4* src = (const float4*)w_recP;
        float4* dst = (float4*)wc;
#pragma unroll
        for (int q = 0; q < (CROWS * HH / 4) / 128; ++q)   // 64 iters
            dst[q * 128 + threadIdx.x] = src[q * 128 + threadIdx.x];
    }

    if (wid == 1) {
        // ---- producer: stage xw chunks into LDS ring (R9-verbatim) ----
        float4 rb[CH];
#pragma unroll
        for (int r = 0; r < CH; ++r)
            rb[r] = *(const float4*)(outp + ((size_t)r * BB + b) * HH + 4 * lane);
#pragma unroll
        for (int r = 0; r < CH; ++r)
            *(float4*)&ring[r * HH + 4 * lane] = rb[r];
        __syncthreads();
        for (int c = 0; c < NCH; ++c) {
            if (c + 1 < NCH) {
                int t0 = (c + 1) * CH;
                int lb = ((c + 1) & 1) * (CH * HH);
                float4 sb[CH];
#pragma unroll
                for (int r = 0; r < CH; ++r)
                    sb[r] = *(const float4*)(outp + ((size_t)(t0 + r) * BB + b) * HH + 4 * lane);
#pragma unroll
                for (int r = 0; r < CH; ++r)
                    *(float4*)&ring[lb + r * HH + 4 * lane] = sb[r];
            }
            __syncthreads();
        }
        return;
    }

    // ---- consumer wave (R9-verbatim skeleton) ----
    int off = b * HH + lane;
    float am[4], bs[4];
#pragma unroll
    for (int j = 0; j < 4; j++) {
        am[j] = DT * clip01(tau_mem[lane + 64 * j]);
        bs[j] = DT * clip01(tau_syn[lane + 64 * j]);
    }

    float vv[4] = {0.f, 0.f, 0.f, 0.f};
    float ii[4] = {0.f, 0.f, 0.f, 0.f};
    float racc[4] = {0.f, 0.f, 0.f, 0.f};
    float zl[4] = {0.f, 0.f, 0.f, 0.f};
    float cur[4], nxt[4];
    unsigned stoff = (unsigned)off;

    __syncthreads();   // wcache + chunk 0 staged

    for (int c = 0; c < NCH; ++c) {
        int lb = (c & 1) * (CH * HH);
#pragma unroll
        for (int j = 0; j < 4; j++)
            cur[j] = ring[lb + lane + 64 * j];
        for (int u = 0; u < CH - 1; ++u) {
#pragma unroll
            for (int j = 0; j < 4; j++)
                nxt[j] = ring[lb + (u + 1) * HH + lane + 64 * j];
            STEP();
#pragma unroll
            for (int j = 0; j < 4; j++)
                cur[j] = nxt[j];
        }
        STEP();        // u = CH-1
        __syncthreads();
    }

    // final state: z_f, v_f, i_f (from registers)
#pragma unroll
    for (int j = 0; j < 4; j++) {
        outp[(size_t)TT * BH + b * HH + lane + 64 * j] = zl[j];
        outp[(size_t)TT * BH + BH + b * HH + lane + 64 * j] = vv[j];
        outp[(size_t)TT * BH + 2 * BH + b * HH + lane + 64 * j] = ii[j];
    }
}

extern "C" void kernel_launch(void* const* d_in, const int* in_sizes, int n_in,
                              void* d_out, int out_size, void* d_ws, size_t ws_size,
                              hipStream_t stream) {
    const float* x       = (const float*)d_in[0];
    const float* w_in    = (const float*)d_in[1];
    const float* w_rec   = (const float*)d_in[2];
    const float* tau_syn = (const float*)d_in[3];
    const float* tau_mem = (const float*)d_in[4];
    float* out = (float*)d_out;

    float* w_inT  = (float*)d_ws;           // 65536 floats
    float* w_recP = w_inT + HH * HH;        // 65536 floats

    transpose2<<<256, 256, 0, stream>>>(w_in, w_rec, w_inT, w_recP);

    dim3 ggrid((BB * TT) / BM, HH / BN);    // (1000, 2)
    gemm_xw<<<ggrid, 256, 0, stream>>>(x, w_inT, out);

    scan_lif<<<BB, 128, 0, stream>>>(tau_syn, tau_mem, w_recP, out);
}